// Round 1
// baseline (710.858 us; speedup 1.0000x reference)
//
#include <hip/hip_runtime.h>
#include <hip/hip_bf16.h>
#include <math.h>

#define Bn 4096
#define Dd 768
#define INV_T 20.0f
#define EPSF 1e-6f
#define DG 4.8516519541e8f   // expf(20.0f): exact exp_ori diagonal

// ws layout (4-byte elements)
#define O_S      0        // 3*4096 row sums (ori_nodiag, gen, aug)
#define O_SMOA   12288    // same-masked (ori_nodiag + aug) sums
#define O_SMG    16384    // same-masked gen sums
#define O_DCO    20480
#define O_DAD    24576
#define O_LOSS   28672    // [0]=ad acc, [1]=co acc
#define O_CNT    29184    // int[128]
#define O_START  29312
#define O_CURSOR 29440
#define O_SORTED 29568    // int[4096]
#define ZERO_BYTES 262144
#define NB_OFF     262144 // bf16 normalized rows: on | gn | an

typedef __attribute__((ext_vector_type(8))) short sh8;
typedef __attribute__((ext_vector_type(4))) float f32x4;

static __device__ __forceinline__ unsigned short f2b(float f) {
    unsigned int u = __float_as_uint(f);
    unsigned int r = (u + 0x7fffu + ((u >> 16) & 1u)) >> 16;  // RNE
    return (unsigned short)r;
}
static __device__ __forceinline__ float blo(unsigned int u) { return __uint_as_float(u << 16); }
static __device__ __forceinline__ float bhi(unsigned int u) { return __uint_as_float(u & 0xffff0000u); }

// ---- normalize rows, write bf16 ----
__global__ void norm_kernel(const float* f0, const float* f1, const float* f2, unsigned short* nb) {
    int r = blockIdx.x, m = blockIdx.y, tid = threadIdx.x;
    const float* src = (m == 0 ? f0 : (m == 1 ? f1 : f2)) + (size_t)r * Dd;
    float x0 = src[tid], x1 = src[tid + 256], x2 = src[tid + 512];
    __shared__ float red[256];
    red[tid] = x0 * x0 + x1 * x1 + x2 * x2;
    __syncthreads();
    for (int s = 128; s > 0; s >>= 1) { if (tid < s) red[tid] += red[tid + s]; __syncthreads(); }
    float inv = rsqrtf(red[0]);
    unsigned short* dst = nb + ((size_t)m * Bn + r) * Dd;
    dst[tid] = f2b(x0 * inv);
    dst[tid + 256] = f2b(x1 * inv);
    dst[tid + 512] = f2b(x2 * inv);
}

// ---- class histogram / prefix / scatter ----
__global__ void hist_kernel(const int* tg, int* I) {
    int i = blockIdx.x * 256 + threadIdx.x;
    if (i < Bn) atomicAdd(&I[O_CNT + tg[i]], 1);
}
__global__ void prefix_kernel(int* I) {
    int acc = 0;
    for (int c = 0; c < 128; ++c) { I[O_START + c] = acc; I[O_CURSOR + c] = acc; acc += I[O_CNT + c]; }
}
__global__ void scatter_kernel(const int* tg, int* I) {
    int i = blockIdx.x * 256 + threadIdx.x;
    if (i < Bn) { int pos = atomicAdd(&I[O_CURSOR + tg[i]], 1); I[O_SORTED + pos] = i; }
}

// ---- fused GEMM + exp row-sum. z selects B-operand (0:on 1:gn 2:an); A is always on.
__launch_bounds__(256)
__global__ void gemm_rowsum(const unsigned short* nb, float* F) {
    int z = blockIdx.z;
    const unsigned short* Ag = nb;
    const unsigned short* Bg = nb + (size_t)z * Bn * Dd;
    int m0 = blockIdx.y * 128, n0 = blockIdx.x * 128;
    int tid = threadIdx.x, lane = tid & 63, wave = tid >> 6;
    int wm = (wave >> 1) * 64, wn = (wave & 1) * 64;
    int lid = lane & 15, q = lane >> 4;
    __shared__ __align__(16) unsigned short Asm[128 * 40];
    __shared__ __align__(16) unsigned short Bsm[128 * 40];
    f32x4 acc[4][4] = {};
    for (int kt = 0; kt < Dd / 32; ++kt) {
        __syncthreads();
        #pragma unroll
        for (int s2 = 0; s2 < 2; ++s2) {
            int c = tid + s2 * 256; int row = c >> 2, seg = c & 3;
            *(int4*)&Asm[row * 40 + seg * 8] = *(const int4*)&Ag[(size_t)(m0 + row) * Dd + kt * 32 + seg * 8];
            *(int4*)&Bsm[row * 40 + seg * 8] = *(const int4*)&Bg[(size_t)(n0 + row) * Dd + kt * 32 + seg * 8];
        }
        __syncthreads();
        sh8 af[4], bf[4];
        #pragma unroll
        for (int i = 0; i < 4; ++i) af[i] = *(const sh8*)&Asm[(wm + i * 16 + lid) * 40 + q * 8];
        #pragma unroll
        for (int j = 0; j < 4; ++j) bf[j] = *(const sh8*)&Bsm[(wn + j * 16 + lid) * 40 + q * 8];
        #pragma unroll
        for (int i = 0; i < 4; ++i)
            #pragma unroll
            for (int j = 0; j < 4; ++j)
                acc[i][j] = __builtin_amdgcn_mfma_f32_16x16x32_bf16(af[i], bf[j], acc[i][j], 0, 0, 0);
    }
    // epilogue: e = exp(s/T); exclude ori diagonal; row-sum over columns
    #pragma unroll
    for (int i = 0; i < 4; ++i)
        #pragma unroll
        for (int reg = 0; reg < 4; ++reg) {
            int grow = m0 + wm + i * 16 + q * 4 + reg;
            float rs = 0.f;
            #pragma unroll
            for (int j = 0; j < 4; ++j) {
                int gcol = n0 + wn + j * 16 + lid;
                float e = expf(acc[i][j][reg] * INV_T);
                if (z == 0 && gcol == grow) e = 0.f;
                rs += e;
            }
            #pragma unroll
            for (int off = 1; off < 16; off <<= 1) rs += __shfl_xor(rs, off);
            if (lid == 0) atomicAdd(&F[O_S + z * Bn + grow], rs);
        }
}

// ---- per same-pair pass. mode 0: masked sums. mode 1: loss terms. ----
__global__ void pair_kernel(const unsigned short* nb, const int* tg, float* F, int mode) {
    const int* I = (const int*)F;
    int b = blockIdx.x, tid = threadIdx.x;
    int i = I[O_SORTED + b];
    int c = tg[i];
    int st = I[O_START + c], n = I[O_CNT + c];
    __shared__ float oi[Dd];
    for (int k = tid; k < Dd; k += 256) oi[k] = blo((unsigned int)nb[(size_t)i * Dd + k]);
    __syncthreads();
    int wave = tid >> 6, lane = tid & 63;
    float dcoi = 0.f, dadi = 0.f;
    if (mode) { dcoi = F[O_DCO + i]; dadi = F[O_DAD + i]; }
    float a0 = 0.f, a1 = 0.f;
    const unsigned int* base = (const unsigned int*)nb;  // bf16 pairs
    for (int p = st + wave; p < st + n; p += 4) {
        int j = I[O_SORTED + p];
        const unsigned int* ro = base + (size_t)j * (Dd / 2);
        const unsigned int* rg = ro + (size_t)Bn * (Dd / 2);
        const unsigned int* ra = ro + (size_t)2 * Bn * (Dd / 2);
        float s1 = 0.f, s2 = 0.f, s3 = 0.f;
        #pragma unroll
        for (int it = 0; it < 6; ++it) {
            int k2 = it * 64 + lane;
            float x0 = oi[2 * k2], x1 = oi[2 * k2 + 1];
            unsigned int u1 = ro[k2]; s1 += x0 * blo(u1) + x1 * bhi(u1);
            unsigned int u2 = rg[k2]; s2 += x0 * blo(u2) + x1 * bhi(u2);
            unsigned int u3 = ra[k2]; s3 += x0 * blo(u3) + x1 * bhi(u3);
        }
        #pragma unroll
        for (int off = 1; off < 64; off <<= 1) {
            s1 += __shfl_xor(s1, off); s2 += __shfl_xor(s2, off); s3 += __shfl_xor(s3, off);
        }
        float eo = expf(s1 * INV_T), eg = expf(s2 * INV_T), ea = expf(s3 * INV_T);
        if (mode == 0) {
            a0 += (j == i ? 0.f : eo) + ea;   // ori diagonal excluded (consistency with gemm)
            a1 += eg;
        } else {
            a0 += -logf(eg / (eg + dadi) + EPSF);
            a1 += -logf(eo / (eo + dcoi) + EPSF) - logf(ea / (ea + dcoi) + EPSF);
        }
    }
    if (lane == 0) {
        if (mode == 0) { atomicAdd(&F[O_SMOA + i], a0); atomicAdd(&F[O_SMG + i], a1); }
        else           { atomicAdd(&F[O_LOSS + 0], a0); atomicAdd(&F[O_LOSS + 1], a1); }
    }
}

__global__ void denom_kernel(float* F) {
    int i = blockIdx.x * 256 + threadIdx.x;
    if (i < Bn) {
        float son = F[O_S + i], sgen = F[O_S + Bn + i], saug = F[O_S + 2 * Bn + i];
        F[O_DCO + i] = (son + saug - F[O_SMOA + i]) + sgen + EPSF;
        F[O_DAD + i] = (sgen - F[O_SMG + i]) + saug + son + DG + EPSF;
    }
}

__global__ void final_kernel(const float* F, float* out) {
    out[0] = F[O_LOSS + 0] * (1.0f / Bn);  // ad_loss
    out[1] = F[O_LOSS + 1] * (1.0f / Bn);  // co_loss
}

extern "C" void kernel_launch(void* const* d_in, const int* in_sizes, int n_in,
                              void* d_out, int out_size, void* d_ws, size_t ws_size,
                              hipStream_t stream) {
    const float* f0 = (const float*)d_in[0];
    const float* f1 = (const float*)d_in[1];
    const float* f2 = (const float*)d_in[2];
    const int* tg = (const int*)d_in[3];
    float* F = (float*)d_ws;
    int* I = (int*)d_ws;
    unsigned short* nb = (unsigned short*)((char*)d_ws + NB_OFF);
    float* out = (float*)d_out;

    hipMemsetAsync(d_ws, 0, ZERO_BYTES, stream);
    norm_kernel<<<dim3(Bn, 3), 256, 0, stream>>>(f0, f1, f2, nb);
    hist_kernel<<<Bn / 256, 256, 0, stream>>>(tg, I);
    prefix_kernel<<<1, 1, 0, stream>>>(I);
    scatter_kernel<<<Bn / 256, 256, 0, stream>>>(tg, I);
    gemm_rowsum<<<dim3(32, 32, 3), 256, 0, stream>>>(nb, F);
    pair_kernel<<<Bn, 256, 0, stream>>>(nb, tg, F, 0);
    denom_kernel<<<Bn / 256, 256, 0, stream>>>(F);
    pair_kernel<<<Bn, 256, 0, stream>>>(nb, tg, F, 1);
    final_kernel<<<1, 1, 0, stream>>>(F, out);
}

// Round 3
// 318.794 us; speedup vs baseline: 2.2298x; 2.2298x over previous
//
#include <hip/hip_runtime.h>
#include <hip/hip_bf16.h>
#include <math.h>

#define Bn 4096
#define Dd 768
#define INV_T 20.0f
#define EPSF 1e-6f
#define DG 4.8516519541e8f   // expf(20.0f): exact exp_ori diagonal

// ws layout (4-byte elements)
#define O_S      0        // 3*4096 row sums (ori_nodiag, gen, aug)
#define O_SMOA   12288    // same-masked (ori_nodiag + aug) sums
#define O_SMG    16384    // same-masked gen sums
#define O_DCO    20480
#define O_DAD    24576
#define O_LOSS   28672    // [0]=ad acc, [1]=co acc
#define O_CNT    29184    // int[128]
#define O_START  29312
#define O_CURSOR 29440
#define O_SORTED 29568    // int[4096]
#define ZERO_BYTES 262144
#define NB_OFF     262144 // bf16 normalized rows: on | gn | an

typedef __attribute__((ext_vector_type(8))) short sh8;
typedef __attribute__((ext_vector_type(4))) float f32x4;

#define AS1 __attribute__((address_space(1)))
#define AS3 __attribute__((address_space(3)))

static __device__ __forceinline__ void gl_lds16(const void* g, void* l) {
    __builtin_amdgcn_global_load_lds((const AS1 void*)g, (AS3 void*)l, 16, 0, 0);
}

static __device__ __forceinline__ unsigned short f2b(float f) {
    unsigned int u = __float_as_uint(f);
    unsigned int r = (u + 0x7fffu + ((u >> 16) & 1u)) >> 16;  // RNE
    return (unsigned short)r;
}
static __device__ __forceinline__ float blo(unsigned int u) { return __uint_as_float(u << 16); }

// ---- normalize rows, write bf16 ----
__global__ void norm_kernel(const float* f0, const float* f1, const float* f2, unsigned short* nb) {
    int r = blockIdx.x, m = blockIdx.y, tid = threadIdx.x;
    const float* src = (m == 0 ? f0 : (m == 1 ? f1 : f2)) + (size_t)r * Dd;
    float x0 = src[tid], x1 = src[tid + 256], x2 = src[tid + 512];
    __shared__ float red[256];
    red[tid] = x0 * x0 + x1 * x1 + x2 * x2;
    __syncthreads();
    for (int s = 128; s > 0; s >>= 1) { if (tid < s) red[tid] += red[tid + s]; __syncthreads(); }
    float inv = rsqrtf(red[0]);
    unsigned short* dst = nb + ((size_t)m * Bn + r) * Dd;
    dst[tid] = f2b(x0 * inv);
    dst[tid + 256] = f2b(x1 * inv);
    dst[tid + 512] = f2b(x2 * inv);
}

// ---- class histogram / prefix / scatter ----
__global__ void hist_kernel(const int* tg, int* I) {
    int i = blockIdx.x * 256 + threadIdx.x;
    if (i < Bn) atomicAdd(&I[O_CNT + tg[i]], 1);
}
__global__ void prefix_kernel(int* I) {
    int acc = 0;
    for (int c = 0; c < 128; ++c) { I[O_START + c] = acc; I[O_CURSOR + c] = acc; acc += I[O_CNT + c]; }
}
__global__ void scatter_kernel(const int* tg, int* I) {
    int i = blockIdx.x * 256 + threadIdx.x;
    if (i < Bn) { int pos = atomicAdd(&I[O_CURSOR + tg[i]], 1); I[O_SORTED + pos] = i; }
}

// ---- fused GEMM + exp row-sum. z selects B-operand (0:on 1:gn 2:an); A is always on.
// global_load_lds width-16 staging (2 segs/thread/matrix = full 128x32 tile),
// XOR seg swizzle (pos = seg ^ (row&3)) -> ds_read_b128 spreads evenly over banks.
__launch_bounds__(256)
__global__ void gemm_rowsum(const unsigned short* nb, float* F) {
    int z = blockIdx.z;
    const unsigned short* Ag = nb;
    const unsigned short* Bg = nb + (size_t)z * Bn * Dd;
    int m0 = blockIdx.y * 128, n0 = blockIdx.x * 128;
    int tid = threadIdx.x, lane = tid & 63, wave = tid >> 6;
    int wm = (wave >> 1) * 64, wn = (wave & 1) * 64;
    int lid = lane & 15, q = lane >> 4;
    __shared__ __align__(16) unsigned short Asm[128 * 32];
    __shared__ __align__(16) unsigned short Bsm[128 * 32];
    // staging: segment c (0..511) -> row c>>2, position c&3 holds global seg (c&3)^(row&3)
    int c0 = tid, c1 = tid + 256;
    int row0 = c0 >> 2, sg0 = (c0 & 3) ^ (row0 & 3);
    int row1 = c1 >> 2, sg1 = (c1 & 3) ^ (row1 & 3);
    const unsigned short* gA0 = Ag + (size_t)(m0 + row0) * Dd + sg0 * 8;
    const unsigned short* gA1 = Ag + (size_t)(m0 + row1) * Dd + sg1 * 8;
    const unsigned short* gB0 = Bg + (size_t)(n0 + row0) * Dd + sg0 * 8;
    const unsigned short* gB1 = Bg + (size_t)(n0 + row1) * Dd + sg1 * 8;
    unsigned short* lA0 = &Asm[c0 * 8];
    unsigned short* lA1 = &Asm[c1 * 8];
    unsigned short* lB0 = &Bsm[c0 * 8];
    unsigned short* lB1 = &Bsm[c1 * 8];
    f32x4 acc[4][4] = {};
    for (int kt = 0; kt < Dd / 32; ++kt) {
        __syncthreads();
        gl_lds16(gA0 + kt * 32, lA0);
        gl_lds16(gA1 + kt * 32, lA1);
        gl_lds16(gB0 + kt * 32, lB0);
        gl_lds16(gB1 + kt * 32, lB1);
        __syncthreads();
        sh8 af[4], bf[4];
        #pragma unroll
        for (int i = 0; i < 4; ++i) {
            int r = wm + i * 16 + lid;
            af[i] = *(const sh8*)&Asm[r * 32 + ((q ^ (r & 3)) * 8)];
        }
        #pragma unroll
        for (int j = 0; j < 4; ++j) {
            int r = wn + j * 16 + lid;
            bf[j] = *(const sh8*)&Bsm[r * 32 + ((q ^ (r & 3)) * 8)];
        }
        #pragma unroll
        for (int i = 0; i < 4; ++i)
            #pragma unroll
            for (int j = 0; j < 4; ++j)
                acc[i][j] = __builtin_amdgcn_mfma_f32_16x16x32_bf16(af[i], bf[j], acc[i][j], 0, 0, 0);
    }
    // epilogue: e = exp(s/T); exclude ori diagonal; row-sum over columns
    #pragma unroll
    for (int i = 0; i < 4; ++i)
        #pragma unroll
        for (int reg = 0; reg < 4; ++reg) {
            int grow = m0 + wm + i * 16 + q * 4 + reg;
            float rs = 0.f;
            #pragma unroll
            for (int j = 0; j < 4; ++j) {
                int gcol = n0 + wn + j * 16 + lid;
                float e = expf(acc[i][j][reg] * INV_T);
                if (z == 0 && gcol == grow) e = 0.f;
                rs += e;
            }
            #pragma unroll
            for (int off = 1; off < 16; off <<= 1) rs += __shfl_xor(rs, off);
            if (lid == 0) atomicAdd(&F[O_S + z * Bn + grow], rs);
        }
}

// ---- per-class MFMA Gram pass. mode 0: masked sums. mode 1: loss terms. ----
__launch_bounds__(256)
__global__ void pair_mfma(const unsigned short* nb, float* F, int mode) {
    const int* I = (const int*)F;
    int c = blockIdx.x;
    int n = I[O_CNT + c];
    __shared__ float r0[4], r1[4];
    if (n == 0) return;
    int st = I[O_START + c];
    int tid = threadIdx.x, wave = tid >> 6, lane = tid & 63;
    int lid = lane & 15, q = lane >> 4;
    int n16 = (n + 15) >> 4;
    int tiles = n16 * n16;
    float a0 = 0.f, a1 = 0.f;
    for (int t = wave; t < tiles; t += 4) {
        int ti = t / n16, tj = t - ti * n16;
        int pa = ti * 16 + lid; if (pa > n - 1) pa = n - 1;
        int pb = tj * 16 + lid; if (pb > n - 1) pb = n - 1;
        int ra = I[O_SORTED + st + pa];
        int rb = I[O_SORTED + st + pb];
        const unsigned short* Ar = nb + (size_t)ra * Dd;
        const unsigned short* Bo = nb + (size_t)rb * Dd;
        const unsigned short* Bg = Bo + (size_t)Bn * Dd;
        const unsigned short* Ba = Bo + (size_t)2 * Bn * Dd;
        f32x4 aco = {0.f, 0.f, 0.f, 0.f}, acg = {0.f, 0.f, 0.f, 0.f}, aca = {0.f, 0.f, 0.f, 0.f};
        #pragma unroll 4
        for (int kt = 0; kt < Dd / 32; ++kt) {
            sh8 af = *(const sh8*)(Ar + kt * 32 + q * 8);
            sh8 bo = *(const sh8*)(Bo + kt * 32 + q * 8);
            sh8 bg = *(const sh8*)(Bg + kt * 32 + q * 8);
            sh8 ba = *(const sh8*)(Ba + kt * 32 + q * 8);
            aco = __builtin_amdgcn_mfma_f32_16x16x32_bf16(af, bo, aco, 0, 0, 0);
            acg = __builtin_amdgcn_mfma_f32_16x16x32_bf16(af, bg, acg, 0, 0, 0);
            aca = __builtin_amdgcn_mfma_f32_16x16x32_bf16(af, ba, aca, 0, 0, 0);
        }
        int col = tj * 16 + lid;
        bool vc = col < n;
        #pragma unroll
        for (int reg = 0; reg < 4; ++reg) {
            int rowp = ti * 16 + q * 4 + reg;
            bool vr = rowp < n;
            float eo = 0.f, eg = 0.f, ea = 0.f;
            if (vr && vc) {
                eo = expf(aco[reg] * INV_T);
                eg = expf(acg[reg] * INV_T);
                ea = expf(aca[reg] * INV_T);
            }
            int i = I[O_SORTED + st + (vr ? rowp : 0)];
            if (mode == 0) {
                float v0 = ((vr && vc && i == rb) ? 0.f : eo) + ea;  // ori diag excluded
                float v1 = eg;
                #pragma unroll
                for (int off = 1; off < 16; off <<= 1) {
                    v0 += __shfl_xor(v0, off);
                    v1 += __shfl_xor(v1, off);
                }
                if (lid == 0 && vr) {
                    atomicAdd(&F[O_SMOA + i], v0);
                    atomicAdd(&F[O_SMG + i], v1);
                }
            } else {
                if (vr && vc) {
                    float dco = F[O_DCO + i], dad = F[O_DAD + i];
                    a0 += -logf(eg / (eg + dad) + EPSF);
                    a1 += -logf(eo / (eo + dco) + EPSF) - logf(ea / (ea + dco) + EPSF);
                }
            }
        }
    }
    if (mode == 1) {
        #pragma unroll
        for (int off = 1; off < 64; off <<= 1) {
            a0 += __shfl_xor(a0, off);
            a1 += __shfl_xor(a1, off);
        }
        if (lane == 0) { r0[wave] = a0; r1[wave] = a1; }
        __syncthreads();
        if (tid == 0) {
            atomicAdd(&F[O_LOSS + 0], r0[0] + r0[1] + r0[2] + r0[3]);
            atomicAdd(&F[O_LOSS + 1], r1[0] + r1[1] + r1[2] + r1[3]);
        }
    }
}

__global__ void denom_kernel(float* F) {
    int i = blockIdx.x * 256 + threadIdx.x;
    if (i < Bn) {
        float son = F[O_S + i], sgen = F[O_S + Bn + i], saug = F[O_S + 2 * Bn + i];
        F[O_DCO + i] = (son + saug - F[O_SMOA + i]) + sgen + EPSF;
        F[O_DAD + i] = (sgen - F[O_SMG + i]) + saug + son + DG + EPSF;
    }
}

__global__ void final_kernel(const float* F, float* out) {
    out[0] = F[O_LOSS + 0] * (1.0f / Bn);  // ad_loss
    out[1] = F[O_LOSS + 1] * (1.0f / Bn);  // co_loss
}

extern "C" void kernel_launch(void* const* d_in, const int* in_sizes, int n_in,
                              void* d_out, int out_size, void* d_ws, size_t ws_size,
                              hipStream_t stream) {
    const float* f0 = (const float*)d_in[0];
    const float* f1 = (const float*)d_in[1];
    const float* f2 = (const float*)d_in[2];
    const int* tg = (const int*)d_in[3];
    float* F = (float*)d_ws;
    int* I = (int*)d_ws;
    unsigned short* nb = (unsigned short*)((char*)d_ws + NB_OFF);
    float* out = (float*)d_out;

    hipMemsetAsync(d_ws, 0, ZERO_BYTES, stream);
    norm_kernel<<<dim3(Bn, 3), 256, 0, stream>>>(f0, f1, f2, nb);
    hist_kernel<<<Bn / 256, 256, 0, stream>>>(tg, I);
    prefix_kernel<<<1, 1, 0, stream>>>(I);
    scatter_kernel<<<Bn / 256, 256, 0, stream>>>(tg, I);
    gemm_rowsum<<<dim3(32, 32, 3), 256, 0, stream>>>(nb, F);
    pair_mfma<<<128, 256, 0, stream>>>(nb, F, 0);
    denom_kernel<<<Bn / 256, 256, 0, stream>>>(F);
    pair_mfma<<<128, 256, 0, stream>>>(nb, F, 1);
    final_kernel<<<1, 1, 0, stream>>>(F, out);
}